// Round 1
// baseline (1503.276 us; speedup 1.0000x reference)
//
#include <hip/hip_runtime.h>
#include <math.h>

#define TLEN 64
#define CIN 128
#define DM 256
#define NH 16
#define DOUT 128
#define PEP 257      // enc row pad (floats): gcd(257,32)=1 -> conflict-free column reads
#define EPS 1e-5f
#define MAX_SHIFT 100

// workspace offsets (floats)
#define O_WT 0        // WTin4: [32 c-chunks][256 d][4 c]  (folded BN1)
#define O_B1 32768    // 256
#define O_WQ 33024    // Wqr: [2 hgrp][256 d][8 h]         (query folded into Wk, /sqrt(8))
#define O_BQ 37120    // 16
#define O_WM 37136    // WmT: [256 d][128 e]               (folded BN2)
#define O_B2 69904    // 128
// total 70032 floats = 280128 bytes of d_ws

__global__ void prep1(const float* __restrict__ W_in, const float* __restrict__ b_in,
                      const float* __restrict__ g, const float* __restrict__ beta,
                      const float* __restrict__ mean, const float* __restrict__ var,
                      float* __restrict__ ws) {
  int i = blockIdx.x * 256 + threadIdx.x;
  if (i < DM * CIN) {
    int d = i >> 7, c = i & 127;
    float s = g[d] * rsqrtf(var[d] + EPS);
    ws[O_WT + (c >> 2) * (DM * 4) + d * 4 + (c & 3)] = W_in[i] * s;
  }
  if (i < DM) {
    float s = g[i] * rsqrtf(var[i] + EPS);
    ws[O_B1 + i] = (b_in[i] - mean[i]) * s + beta[i];
  }
}

__global__ void prep2(const float* __restrict__ query, const float* __restrict__ Wk,
                      const float* __restrict__ bk, float* __restrict__ ws) {
  int i = blockIdx.x * 256 + threadIdx.x;
  const float inv = 0.35355339059327373f; // 1/sqrt(8)
  if (i < DM * NH) {
    int d = i >> 4, h = i & 15;
    float a = 0.f;
    for (int j = 0; j < 8; ++j) a += query[h * 8 + j] * Wk[(h * 8 + j) * DM + d];
    ws[O_WQ + (h >> 3) * (DM * 8) + d * 8 + (h & 7)] = a * inv;
  }
  if (i < NH) {
    float a = 0.f;
    for (int j = 0; j < 8; ++j) a += query[i * 8 + j] * bk[i * 8 + j];
    ws[O_BQ + i] = a * inv;
  }
}

__global__ void prep3(const float* __restrict__ W_mlp, const float* __restrict__ b_mlp,
                      const float* __restrict__ g, const float* __restrict__ beta,
                      const float* __restrict__ mean, const float* __restrict__ var,
                      float* __restrict__ ws) {
  int i = blockIdx.x * 256 + threadIdx.x;
  if (i < DOUT * DM) {
    int e = i >> 8, dd = i & 255;
    float s = g[e] * rsqrtf(var[e] + EPS);
    ws[O_WM + dd * DOUT + e] = W_mlp[i] * s;
  }
  if (i < DOUT) {
    float s = g[i] * rsqrtf(var[i] + EPS);
    ws[O_B2 + i] = (b_mlp[i] - mean[i]) * s + beta[i];
  }
}

__global__ __launch_bounds__(512, 1)
void ltae_main(const float* __restrict__ x, const int* __restrict__ pos,
               const float* __restrict__ ptab, const float* __restrict__ ws,
               float* __restrict__ out) {
  __shared__ float sx[TLEN * CIN];   // 32 KB; reused as reduction scratch after phase 1
  __shared__ float senc[TLEN * PEP]; // 65792 B
  __shared__ float ss[TLEN * 17];    // scores / att, pad 17 (gcd(17,32)=1)
  __shared__ float sy[DM];
  __shared__ int spos[TLEN];

  const int b = blockIdx.x;
  const int tid = threadIdx.x;

  // ---- phase 0: stage x[b] (coalesced float4), positions ----
  {
    const float4* xg = (const float4*)(x + (size_t)b * (TLEN * CIN));
    float4* xl = (float4*)sx;
#pragma unroll
    for (int i = 0; i < 4; ++i) xl[tid + 512 * i] = xg[tid + 512 * i];
    if (tid < TLEN) spos[tid] = pos[b * TLEN + tid] + MAX_SHIFT;
  }
  __syncthreads();

  // ---- phase 1: GEMM1 + BN1(folded) + ReLU + PE -> senc ----
  // thread owns d = tid&255, half the t's. x reads are wave-uniform LDS broadcasts;
  // weight reads are coalesced float4 (pre-transposed chunk-major layout).
  {
    const int d = tid & 255;
    const int t0 = (tid >> 8) * 32;
    float acc[32];
#pragma unroll
    for (int i = 0; i < 32; ++i) acc[i] = 0.f;
    const float4* wt = (const float4*)(ws + O_WT);
    float4 wn = wt[d]; // prefetch chunk 0
    for (int c4 = 0; c4 < 32; ++c4) {
      const float4 w = wn;
      if (c4 < 31) wn = wt[(c4 + 1) * DM + d];
#pragma unroll
      for (int i = 0; i < 32; ++i) {
        const float4 xv = *(const float4*)&sx[(t0 + i) * CIN + c4 * 4];
        acc[i] = fmaf(xv.x, w.x, acc[i]);
        acc[i] = fmaf(xv.y, w.y, acc[i]);
        acc[i] = fmaf(xv.z, w.z, acc[i]);
        acc[i] = fmaf(xv.w, w.w, acc[i]);
      }
    }
    const float bb = ws[O_B1 + d];
#pragma unroll
    for (int i = 0; i < 32; ++i) {
      const int t = t0 + i;
      float v = acc[i] + bb;
      v = fmaxf(v, 0.f);
      v += ptab[(size_t)spos[t] * DM + d];
      senc[t * PEP + d] = v;
    }
  }
  __syncthreads();

  // ---- phase 2: folded score GEMM  s[t][h] = enc[t,:] . Wq[:,h] + bq ----
  // thread = (t, hgrp(8 h's), d-quarter). Wq reads wave-uniform; enc reads conflict-free.
  {
    const int t = tid & 63;
    const int hg = (tid >> 6) & 1;
    const int dq = tid >> 7;
    const float* wq = ws + O_WQ + hg * (DM * 8);
    const int d0 = dq * 64;
    float p[8];
#pragma unroll
    for (int k = 0; k < 8; ++k) p[k] = 0.f;
    for (int dd = 0; dd < 64; ++dd) {
      const float e = senc[t * PEP + d0 + dd];
      const float4 q0 = *(const float4*)&wq[(d0 + dd) * 8];
      const float4 q1 = *(const float4*)&wq[(d0 + dd) * 8 + 4];
      p[0] = fmaf(e, q0.x, p[0]);
      p[1] = fmaf(e, q0.y, p[1]);
      p[2] = fmaf(e, q0.z, p[2]);
      p[3] = fmaf(e, q0.w, p[3]);
      p[4] = fmaf(e, q1.x, p[4]);
      p[5] = fmaf(e, q1.y, p[5]);
      p[6] = fmaf(e, q1.z, p[6]);
      p[7] = fmaf(e, q1.w, p[7]);
    }
    const int base = t * 65 + hg * 32 + dq * 8; // pad 65/t: conflict-free
#pragma unroll
    for (int k = 0; k < 8; ++k) sx[base + k] = p[k];
  }
  __syncthreads();

  // ---- phase 2b: reduce d-quarters + bias -> ss[t][h] ----
  {
#pragma unroll
    for (int r = 0; r < 2; ++r) {
      const int pidx = tid + r * 512;
      const int t = pidx >> 4, h = pidx & 15;
      const int hg = h >> 3, hh = h & 7;
      float s = ws[O_BQ + h];
#pragma unroll
      for (int dq = 0; dq < 4; ++dq) s += sx[t * 65 + hg * 32 + dq * 8 + hh];
      ss[t * 17 + h] = s;
    }
  }
  __syncthreads();

  // ---- phase 2c: softmax over t, per head (wave w handles h=2w,2w+1) ----
  {
    const int lane = tid & 63;
    const int w = tid >> 6;
#pragma unroll
    for (int r = 0; r < 2; ++r) {
      const int h = w * 2 + r;
      const float v = ss[lane * 17 + h];
      float m = v;
#pragma unroll
      for (int off = 32; off; off >>= 1) m = fmaxf(m, __shfl_xor(m, off));
      const float e = __expf(v - m);
      float den = e;
#pragma unroll
      for (int off = 32; off; off >>= 1) den += __shfl_xor(den, off);
      ss[lane * 17 + h] = e / den;
    }
  }
  __syncthreads();

  // ---- phase 3: y[h,e] = sum_t att[t,h] * enc[t, h*16+e] ----
  if (tid < DM) {
    const int h = tid >> 4;
    float a0 = 0.f, a1 = 0.f;
    for (int t = 0; t < TLEN; t += 2) {
      a0 = fmaf(ss[t * 17 + h], senc[t * PEP + tid], a0);
      a1 = fmaf(ss[(t + 1) * 17 + h], senc[(t + 1) * PEP + tid], a1);
    }
    sy[tid] = a0 + a1;
  }
  __syncthreads();

  // ---- phase 4: MLP + BN2(folded) + ReLU ----
  {
    const int e = tid & 127;
    const int dq = tid >> 7;
    const float* wm = ws + O_WM;
    float a0 = 0.f, a1 = 0.f;
    const int d0 = dq * 64;
    for (int dd = 0; dd < 64; dd += 2) {
      a0 = fmaf(sy[d0 + dd], wm[(d0 + dd) * DOUT + e], a0);
      a1 = fmaf(sy[d0 + dd + 1], wm[(d0 + dd + 1) * DOUT + e], a1);
    }
    sx[dq * 128 + e] = a0 + a1;
  }
  __syncthreads();
  if (tid < DOUT) {
    const float o = ws[O_B2 + tid] + sx[tid] + sx[128 + tid] + sx[256 + tid] + sx[384 + tid];
    out[(size_t)b * DOUT + tid] = fmaxf(o, 0.f);
  }
}

extern "C" void kernel_launch(void* const* d_in, const int* in_sizes, int n_in,
                              void* d_out, int out_size, void* d_ws, size_t ws_size,
                              hipStream_t stream) {
  const float* x      = (const float*)d_in[0];
  const int*   pos    = (const int*)d_in[1];
  const float* W_in   = (const float*)d_in[2];
  const float* b_in   = (const float*)d_in[3];
  const float* g1     = (const float*)d_in[4];
  const float* beta1  = (const float*)d_in[5];
  const float* m1     = (const float*)d_in[6];
  const float* v1     = (const float*)d_in[7];
  const float* ptab   = (const float*)d_in[8];
  const float* query  = (const float*)d_in[9];
  const float* Wk     = (const float*)d_in[10];
  const float* bk     = (const float*)d_in[11];
  const float* W_mlp  = (const float*)d_in[12];
  const float* b_mlp  = (const float*)d_in[13];
  const float* g2     = (const float*)d_in[14];
  const float* beta2  = (const float*)d_in[15];
  const float* m2     = (const float*)d_in[16];
  const float* v2     = (const float*)d_in[17];
  float* ws = (float*)d_ws;
  float* o  = (float*)d_out;

  hipLaunchKernelGGL(prep1, dim3(128), dim3(256), 0, stream, W_in, b_in, g1, beta1, m1, v1, ws);
  hipLaunchKernelGGL(prep2, dim3(16), dim3(256), 0, stream, query, Wk, bk, ws);
  hipLaunchKernelGGL(prep3, dim3(128), dim3(256), 0, stream, W_mlp, b_mlp, g2, beta2, m2, v2, ws);
  hipLaunchKernelGGL(ltae_main, dim3(8192), dim3(512), 0, stream, x, pos, ptab, ws, o);
}